// Round 12
// baseline (1302.408 us; speedup 1.0000x reference)
//
#include <hip/hip_runtime.h>
#include <hip/hip_cooperative_groups.h>
#include <stdint.h>

namespace cg = cooperative_groups;

static constexpr int kN   = 50000;   // nodes
static constexpr int kCap = 64;      // adjacency capacity per node (Poisson(12) tail @64 ~ 1e-25)

typedef __attribute__((ext_vector_type(8))) _Float16 f16x8;  // MFMA A/B fragment
typedef __attribute__((ext_vector_type(2))) _Float16 f16x2;  // packed pair -> v_pk_add_f16
typedef __attribute__((ext_vector_type(4))) float f32x4;     // MFMA 16x16 accumulator

// ---------------- threefry2x32-20 (verified vs Random123 KAT) ----------------
__device__ __forceinline__ uint32_t rotl32(uint32_t v, uint32_t r) {
  return (v << r) | (v >> (32u - r));
}

__device__ __forceinline__ uint2 threefry2x32(uint32_t k0, uint32_t k1,
                                              uint32_t x0, uint32_t x1) {
  const uint32_t k2 = k0 ^ k1 ^ 0x1BD11BDAu;
  x0 += k0; x1 += k1;
#define TFR(r) { x0 += x1; x1 = rotl32(x1, r); x1 ^= x0; }
  TFR(13u) TFR(15u) TFR(26u) TFR(6u)
  x0 += k1; x1 += k2 + 1u;
  TFR(17u) TFR(29u) TFR(16u) TFR(24u)
  x0 += k2; x1 += k0 + 2u;
  TFR(13u) TFR(15u) TFR(26u) TFR(6u)
  x0 += k0; x1 += k1 + 3u;
  TFR(17u) TFR(29u) TFR(16u) TFR(24u)
  x0 += k1; x1 += k2 + 4u;
  TFR(13u) TFR(15u) TFR(26u) TFR(6u)
  x0 += k2; x1 += k0 + 5u;
#undef TFR
  return make_uint2(x0, x1);
}

__device__ __forceinline__ bool drop_elem(uint32_t j) {
  const uint2 r = threefry2x32(0u, 42u, 0u, j);
  return ((r.x ^ r.y) >> 31) != 0u;
}

// ---------------- f16 pack/unpack ----------------
union PairU { f16x2 h; uint32_t u; };
__device__ __forceinline__ uint32_t pack_f16x2(float lo, float hi) {
  PairU p; p.h[0] = (_Float16)lo; p.h[1] = (_Float16)hi; return p.u;
}
__device__ __forceinline__ float f16_lo(f16x2 v) { return (float)v[0]; }
__device__ __forceinline__ float f16_hi(f16x2 v) { return (float)v[1]; }

union FragU { uint4 q; f16x8 f; };

// ================= single persistent cooperative kernel =================
// P0 zero cnt/zpad + prep W1T/W2T -> P1 build_adj -> P2 gemm1(MFMA) ->
// P3 agg1(+relu+dropout) -> P4 gemm2(MFMA) -> P5 agg_out.
// No LDS anywhere: GEMM B-fragments read directly from global W1T/W2T
// (32/16 KB, L1/L2-resident). All loops grid-strided; 5 grid.sync()s.
__global__ void __launch_bounds__(256, 8) gin_mega(
    const float* __restrict__ x, const int* __restrict__ src,
    const int* __restrict__ dst, int E,
    const float* __restrict__ W1, const float* __restrict__ b1,
    const float* __restrict__ W2, const float* __restrict__ b2,
    uint32_t* __restrict__ W1T, uint32_t* __restrict__ W2T,
    int* __restrict__ cnt, int* __restrict__ adj,
    uint32_t* __restrict__ z1h, uint32_t* __restrict__ hh,
    uint32_t* __restrict__ z2h, uint32_t* __restrict__ zpad,
    float* __restrict__ out) {
  cg::grid_group grid = cg::this_grid();
  const int tid    = threadIdx.x;
  const int gsz    = gridDim.x * 256;
  const int gtid   = blockIdx.x * 256 + tid;
  const int lane   = tid & 63;
  const int gwave  = gtid >> 6;
  const int gwaves = gridDim.x * 4;

  // ---- P0: zero cnt + zpad, prep W1T/W2T ----
  for (int v = gtid; v < kN; v += gsz) cnt[v] = 0;
  if (gtid < 64) zpad[gtid] = 0;
  for (int v = gtid; v < 128 * 64 + 64 * 64; v += gsz) {
    if (v < 128 * 64) {
      const int n = v >> 6, i = v & 63;
      W1T[v] = pack_f16x2(W1[(size_t)(2 * i) * 128 + n], W1[(size_t)(2 * i + 1) * 128 + n]);
    } else {
      const int w = v - 128 * 64;
      const int n = w >> 6, i = w & 63;
      W2T[w] = pack_f16x2(W2[(size_t)(2 * i) * 64 + n], W2[(size_t)(2 * i + 1) * 64 + n]);
    }
  }
  __threadfence();
  grid.sync();

  // ---- P1: build adjacency ----
  for (int e = gtid; e < E; e += gsz) {
    const int d = dst[e];
    const int slot = atomicAdd(&cnt[d], 1);
    if (slot < kCap) adj[d * kCap + slot] = src[e];
  }
  __threadfence();
  grid.sync();

  // ---- P2: gemm1 (MFMA): z1h = pack_f16(x @ W1) ----
  // task = (rb, column-group); 3125 rb x 2 cg = 6250 wave-tasks (3125*16 = 50000 exact).
  // Layouts (HW-verified r8): A[m=lane&15][k=quad*8+j], B[n=lane&15][k=quad*8+j],
  // D: col=lane&15, row=quad*4+reg.
  {
    const int quad = lane >> 4, mrow = lane & 15;
    for (int task = gwave; task < 6250; task += gwaves) {
      const int rb = task >> 1, cgp = task & 1;
      const int n0 = rb * 16;
      const float* xp = x + (size_t)(n0 + mrow) * 128 + quad * 8;
      f32x4 acc[4] = {{0.f,0.f,0.f,0.f},{0.f,0.f,0.f,0.f},{0.f,0.f,0.f,0.f},{0.f,0.f,0.f,0.f}};
#pragma unroll
      for (int kb = 0; kb < 4; ++kb) {
        const float4 lo = *reinterpret_cast<const float4*>(xp + kb * 32);
        const float4 hi = *reinterpret_cast<const float4*>(xp + kb * 32 + 4);
        FragU a;
        a.q = make_uint4(pack_f16x2(lo.x, lo.y), pack_f16x2(lo.z, lo.w),
                         pack_f16x2(hi.x, hi.y), pack_f16x2(hi.z, hi.w));
#pragma unroll
        for (int ct = 0; ct < 4; ++ct) {
          const int n = cgp * 64 + ct * 16 + mrow;
          FragU b;
          b.q = *reinterpret_cast<const uint4*>(W1T + n * 64 + kb * 16 + quad * 4);
          acc[ct] = __builtin_amdgcn_mfma_f32_16x16x32_f16(a.f, b.f, acc[ct], 0, 0, 0);
        }
      }
#pragma unroll
      for (int ct = 0; ct < 4; ++ct) {
#pragma unroll
        for (int r = 0; r < 4; ++r) {
          const float v = acc[ct][r];
          const float vOdd = __shfl(v, lane | 1);
          if ((lane & 1) == 0) {
            const int row = n0 + quad * 4 + r;
            z1h[(size_t)row * 64 + cgp * 32 + ct * 8 + (mrow >> 1)] = pack_f16x2(v, vOdd);
          }
        }
      }
    }
  }
  __threadfence();
  grid.sync();

  // ---- P3: agg1: hh = pack_f16(dropout(relu(z1[n] + sum z1[adj] + b1))) ----
  // 2 nodes per wave, 32 loads in flight.
  {
    const f16x2* z1 = (const f16x2*)z1h;
    const f16x2* zp = (const f16x2*)zpad;
    for (int p = gwave; p < kN / 2; p += gwaves) {
      const int nA = p * 2, nB = p * 2 + 1;
      const int vaA = adj[(size_t)nA * kCap + lane];
      const int vaB = adj[(size_t)nB * kCap + lane];
      int dA = __builtin_amdgcn_readfirstlane(cnt[nA]); if (dA > kCap) dA = kCap;
      int dB = __builtin_amdgcn_readfirstlane(cnt[nB]); if (dB > kCap) dB = kCap;
      const int dm = (dA > dB) ? dA : dB;

      f16x2 sA0 = z1[(size_t)nA * 64 + lane];
      f16x2 sB0 = z1[(size_t)nB * 64 + lane];
      f16x2 sA1 = (f16x2)0, sA2 = (f16x2)0, sA3 = (f16x2)0;
      f16x2 sB1 = (f16x2)0, sB2 = (f16x2)0, sB3 = (f16x2)0;

      int e = 0;
      while (e < dm) {
        f16x2 vA[16], vB[16];
#pragma unroll
        for (int j = 0; j < 16; ++j) {
          const int ee = e + j;
          const int ia = __builtin_amdgcn_readlane(vaA, ee);
          const f16x2* ba = (ee < dA) ? (z1 + (size_t)ia * 64) : zp;  // scalar select
          vA[j] = ba[lane];
        }
#pragma unroll
        for (int j = 0; j < 16; ++j) {
          const int ee = e + j;
          const int ib = __builtin_amdgcn_readlane(vaB, ee);
          const f16x2* bb = (ee < dB) ? (z1 + (size_t)ib * 64) : zp;
          vB[j] = bb[lane];
        }
#pragma unroll
        for (int j = 0; j < 16; ++j) {
          if ((j & 3) == 0)      { sA0 += vA[j]; sB0 += vB[j]; }
          else if ((j & 3) == 1) { sA1 += vA[j]; sB1 += vB[j]; }
          else if ((j & 3) == 2) { sA2 += vA[j]; sB2 += vB[j]; }
          else                   { sA3 += vA[j]; sB3 += vB[j]; }
        }
        e += 16;
      }

      const float2 bb = *reinterpret_cast<const float2*>(b1 + 2 * lane);
      {
        const f16x2 s = (sA0 + sA1) + (sA2 + sA3);
        float hx = fmaxf(f16_lo(s) + bb.x, 0.0f);
        float hy = fmaxf(f16_hi(s) + bb.y, 0.0f);
        const uint32_t j0 = (uint32_t)nA * 128u + 2u * (uint32_t)lane;
        hx = drop_elem(j0)      ? 0.0f : hx * 2.0f;
        hy = drop_elem(j0 + 1u) ? 0.0f : hy * 2.0f;
        hh[(size_t)nA * 64 + lane] = pack_f16x2(hx, hy);
      }
      {
        const f16x2 s = (sB0 + sB1) + (sB2 + sB3);
        float hx = fmaxf(f16_lo(s) + bb.x, 0.0f);
        float hy = fmaxf(f16_hi(s) + bb.y, 0.0f);
        const uint32_t j0 = (uint32_t)nB * 128u + 2u * (uint32_t)lane;
        hx = drop_elem(j0)      ? 0.0f : hx * 2.0f;
        hy = drop_elem(j0 + 1u) ? 0.0f : hy * 2.0f;
        hh[(size_t)nB * 64 + lane] = pack_f16x2(hx, hy);
      }
    }
  }
  __threadfence();
  grid.sync();

  // ---- P4: gemm2 (MFMA): z2h = pack_f16(h @ W2) ----
  {
    const int quad = lane >> 4, mrow = lane & 15;
    for (int rb = gwave; rb < 3125; rb += gwaves) {
      const int n0 = rb * 16;
      const uint32_t* hp = hh + (size_t)(n0 + mrow) * 64 + quad * 4;
      f32x4 acc[4] = {{0.f,0.f,0.f,0.f},{0.f,0.f,0.f,0.f},{0.f,0.f,0.f,0.f},{0.f,0.f,0.f,0.f}};
#pragma unroll
      for (int kb = 0; kb < 4; ++kb) {
        FragU a;
        a.q = *reinterpret_cast<const uint4*>(hp + kb * 16);
#pragma unroll
        for (int ct = 0; ct < 4; ++ct) {
          const int n = ct * 16 + mrow;
          FragU b;
          b.q = *reinterpret_cast<const uint4*>(W2T + n * 64 + kb * 16 + quad * 4);
          acc[ct] = __builtin_amdgcn_mfma_f32_16x16x32_f16(a.f, b.f, acc[ct], 0, 0, 0);
        }
      }
#pragma unroll
      for (int ct = 0; ct < 4; ++ct) {
#pragma unroll
        for (int r = 0; r < 4; ++r) {
          const float v = acc[ct][r];
          const float vOdd = __shfl(v, lane | 1);
          if ((lane & 1) == 0) {
            const int row = n0 + quad * 4 + r;
            z2h[(size_t)row * 32 + ct * 8 + (mrow >> 1)] = pack_f16x2(v, vOdd);
          }
        }
      }
    }
  }
  __threadfence();
  grid.sync();

  // ---- P5: agg_out: out = z2[n] + sum z2[adj] + b2 ----
  // 2 nodes per wave; all 64 lanes accumulate word (lane&31) (mirrored halves).
  {
    const f16x2* z2 = (const f16x2*)z2h;
    const f16x2* zp = (const f16x2*)zpad;
    const int word = lane & 31;
    for (int p = gwave; p < kN / 2; p += gwaves) {
      const int nA = p * 2, nB = p * 2 + 1;
      const int vaA = adj[(size_t)nA * kCap + lane];
      const int vaB = adj[(size_t)nB * kCap + lane];
      int dA = __builtin_amdgcn_readfirstlane(cnt[nA]); if (dA > kCap) dA = kCap;
      int dB = __builtin_amdgcn_readfirstlane(cnt[nB]); if (dB > kCap) dB = kCap;
      const int dm = (dA > dB) ? dA : dB;

      f16x2 sA0 = z2[(size_t)nA * 32 + word];
      f16x2 sB0 = z2[(size_t)nB * 32 + word];
      f16x2 sA1 = (f16x2)0, sA2 = (f16x2)0, sA3 = (f16x2)0;
      f16x2 sB1 = (f16x2)0, sB2 = (f16x2)0, sB3 = (f16x2)0;

      int e = 0;
      while (e < dm) {
        f16x2 vA[16], vB[16];
#pragma unroll
        for (int j = 0; j < 16; ++j) {
          const int ee = e + j;
          const int ia = __builtin_amdgcn_readlane(vaA, ee);
          const f16x2* ba = (ee < dA) ? (z2 + (size_t)ia * 32) : zp;
          vA[j] = ba[word];
        }
#pragma unroll
        for (int j = 0; j < 16; ++j) {
          const int ee = e + j;
          const int ib = __builtin_amdgcn_readlane(vaB, ee);
          const f16x2* bb = (ee < dB) ? (z2 + (size_t)ib * 32) : zp;
          vB[j] = bb[word];
        }
#pragma unroll
        for (int j = 0; j < 16; ++j) {
          if ((j & 3) == 0)      { sA0 += vA[j]; sB0 += vB[j]; }
          else if ((j & 3) == 1) { sA1 += vA[j]; sB1 += vB[j]; }
          else if ((j & 3) == 2) { sA2 += vA[j]; sB2 += vB[j]; }
          else                   { sA3 += vA[j]; sB3 += vB[j]; }
        }
        e += 16;
      }

      const float bias = b2[lane];
      {
        PairU s; s.h = (sA0 + sA1) + (sA2 + sA3);
        PairU g; g.u = (uint32_t)__shfl((int)s.u, lane >> 1);
        const float v = (lane & 1) ? f16_hi(g.h) : f16_lo(g.h);
        out[(size_t)nA * 64 + lane] = v + bias;
      }
      {
        PairU s; s.h = (sB0 + sB1) + (sB2 + sB3);
        PairU g; g.u = (uint32_t)__shfl((int)s.u, lane >> 1);
        const float v = (lane & 1) ? f16_hi(g.h) : f16_lo(g.h);
        out[(size_t)nB * 64 + lane] = v + bias;
      }
    }
  }
}

// ---------------- launch ----------------
extern "C" void kernel_launch(void* const* d_in, const int* in_sizes, int n_in,
                              void* d_out, int out_size, void* d_ws, size_t ws_size,
                              hipStream_t stream) {
  const float* x  = (const float*)d_in[0];
  const int*   ei = (const int*)d_in[1];
  const float* W1 = (const float*)d_in[2];
  const float* b1 = (const float*)d_in[3];
  const float* W2 = (const float*)d_in[4];
  const float* b2 = (const float*)d_in[5];
  float* out = (float*)d_out;

  int E = in_sizes[1] / 2;  // edge_index is (2, E), int32 on device
  const int* src = ei;
  const int* dst = ei + E;

  // d_ws layout:
  uint32_t* zpad = (uint32_t*)d_ws;                        // 64 dwords = 256 B
  int*      cnt  = (int*)((char*)d_ws + 256);              // 50000 ints
  int*      adj  = cnt + kN;                               // 50000*64 ints = 12.8 MB
  uint32_t* z1h  = (uint32_t*)(adj + (size_t)kN * kCap);   // 50000*64 dwords = 12.8 MB
  uint32_t* hh   = z1h + (size_t)kN * 64;                  // 50000*64 dwords = 12.8 MB
  uint32_t* z2h  = hh + (size_t)kN * 64;                   // 50000*32 dwords = 6.4 MB
  uint32_t* W1T  = z2h + (size_t)kN * 32;                  // 8192 dwords = 32 KB
  uint32_t* W2T  = W1T + 128 * 64;                         // 4096 dwords = 16 KB

  // co-resident grid size (pure host-side query; capture-safe)
  int occ = 0;
  if (hipOccupancyMaxActiveBlocksPerMultiprocessor(&occ, gin_mega, 256, 0) != hipSuccess || occ < 1)
    occ = 4;
  if (occ > 8) occ = 8;
  const int grid = occ * 256;  // 256 CUs on MI355X

  void* params[] = {
    (void*)&x, (void*)&src, (void*)&dst, (void*)&E,
    (void*)&W1, (void*)&b1, (void*)&W2, (void*)&b2,
    (void*)&W1T, (void*)&W2T, (void*)&cnt, (void*)&adj,
    (void*)&z1h, (void*)&hh, (void*)&z2h, (void*)&zpad, (void*)&out
  };
  hipLaunchCooperativeKernel(reinterpret_cast<void*>(gin_mega),
                             dim3(grid), dim3(256), params, 0, stream);
}

// Round 13
// 191.749 us; speedup vs baseline: 6.7923x; 6.7923x over previous
//
#include <hip/hip_runtime.h>
#include <stdint.h>

static constexpr int kN   = 50000;   // nodes
static constexpr int kCap = 64;      // adjacency capacity per node (Poisson(12) tail @64 ~ 1e-25)
static constexpr int kPrepBlocks = 48;  // 48*256 = 12288 >= 128*64+64*64 weight dwords

typedef __attribute__((ext_vector_type(8))) _Float16 f16x8;  // MFMA A/B fragment
typedef __attribute__((ext_vector_type(2))) _Float16 f16x2;  // packed pair -> v_pk_add_f16
typedef __attribute__((ext_vector_type(4))) float f32x4;     // MFMA 16x16 accumulator

// ---------------- threefry2x32-20 (verified vs Random123 KAT) ----------------
__device__ __forceinline__ uint32_t rotl32(uint32_t v, uint32_t r) {
  return (v << r) | (v >> (32u - r));
}

__device__ __forceinline__ uint2 threefry2x32(uint32_t k0, uint32_t k1,
                                              uint32_t x0, uint32_t x1) {
  const uint32_t k2 = k0 ^ k1 ^ 0x1BD11BDAu;
  x0 += k0; x1 += k1;
#define TFR(r) { x0 += x1; x1 = rotl32(x1, r); x1 ^= x0; }
  TFR(13u) TFR(15u) TFR(26u) TFR(6u)
  x0 += k1; x1 += k2 + 1u;
  TFR(17u) TFR(29u) TFR(16u) TFR(24u)
  x0 += k2; x1 += k0 + 2u;
  TFR(13u) TFR(15u) TFR(26u) TFR(6u)
  x0 += k0; x1 += k1 + 3u;
  TFR(17u) TFR(29u) TFR(16u) TFR(24u)
  x0 += k1; x1 += k2 + 4u;
  TFR(13u) TFR(15u) TFR(26u) TFR(6u)
  x0 += k2; x1 += k0 + 5u;
#undef TFR
  return make_uint2(x0, x1);
}

__device__ __forceinline__ bool drop_elem(uint32_t j) {
  const uint2 r = threefry2x32(0u, 42u, 0u, j);
  return ((r.x ^ r.y) >> 31) != 0u;
}

// ---------------- f16 pack/unpack ----------------
union PairU { f16x2 h; uint32_t u; };
__device__ __forceinline__ uint32_t pack_f16x2(float lo, float hi) {
  PairU p; p.h[0] = (_Float16)lo; p.h[1] = (_Float16)hi; return p.u;
}
__device__ __forceinline__ f16x2 as_f16x2(uint32_t u) { PairU p; p.u = u; return p.h; }
__device__ __forceinline__ float f16_lo(f16x2 v) { return (float)v[0]; }
__device__ __forceinline__ float f16_hi(f16x2 v) { return (float)v[1]; }

union FragU { uint4 q; f16x8 f; };

// ---------------- K0: prep_wT + build_adj (block-range split, both LDS-free) ----
__global__ __launch_bounds__(256) void k0_prep_build(
    const float* __restrict__ W1, const float* __restrict__ W2,
    uint32_t* __restrict__ W1T, uint32_t* __restrict__ W2T,
    const int* __restrict__ src, const int* __restrict__ dst,
    int* __restrict__ cnt, int* __restrict__ adj, int E) {
  if (blockIdx.x < kPrepBlocks) {
    const int v = blockIdx.x * 256 + threadIdx.x;
    if (v < 128 * 64) {
      const int n = v >> 6, i = v & 63;
      W1T[v] = pack_f16x2(W1[(size_t)(2 * i) * 128 + n], W1[(size_t)(2 * i + 1) * 128 + n]);
    } else if (v < 128 * 64 + 64 * 64) {
      const int w = v - 128 * 64;
      const int n = w >> 6, i = w & 63;
      W2T[w] = pack_f16x2(W2[(size_t)(2 * i) * 64 + n], W2[(size_t)(2 * i + 1) * 64 + n]);
    }
    return;
  }
  const int base = (blockIdx.x - kPrepBlocks) * 1024 + threadIdx.x;
  int d[4], s[4];
  bool ok[4];
#pragma unroll
  for (int j = 0; j < 4; ++j) {
    const int e = base + j * 256;
    ok[j] = (e < E);
    d[j] = ok[j] ? dst[e] : 0;
    s[j] = ok[j] ? src[e] : 0;
  }
  int slot[4];
#pragma unroll
  for (int j = 0; j < 4; ++j)
    slot[j] = ok[j] ? atomicAdd(&cnt[d[j]], 1) : kCap;
#pragma unroll
  for (int j = 0; j < 4; ++j)
    if (ok[j] && slot[j] < kCap) adj[d[j] * kCap + slot[j]] = s[j];
}

// ---------------- GEMM1 (MFMA f16): z1h = pack_f16(x @ W1) ----------------
__global__ __launch_bounds__(256, 4) void gemm1_mfma(
    const float* __restrict__ x, const uint32_t* __restrict__ W1T,
    uint32_t* __restrict__ z1h) {
  __shared__ uint32_t WT[128 * 68];  // 34 KB
  for (int v = threadIdx.x; v < 128 * 64; v += 256)
    WT[(v >> 6) * 68 + (v & 63)] = W1T[v];
  __syncthreads();

  const int lane = threadIdx.x & 63;
  const int wid  = threadIdx.x >> 6;
  const int rb   = blockIdx.x * 2 + (wid >> 1);  // 1563 blocks -> rb 0..3125
  if (rb >= 3125) return;
  const int cg   = wid & 1;
  const int n0   = rb * 16;
  const int quad = lane >> 4;
  const int mrow = lane & 15;

  const float* xp = x + (size_t)(n0 + mrow) * 128 + quad * 8;
  f32x4 acc[4] = {{0.f,0.f,0.f,0.f},{0.f,0.f,0.f,0.f},{0.f,0.f,0.f,0.f},{0.f,0.f,0.f,0.f}};

#pragma unroll
  for (int kb = 0; kb < 4; ++kb) {
    const float4 lo = *reinterpret_cast<const float4*>(xp + kb * 32);
    const float4 hi = *reinterpret_cast<const float4*>(xp + kb * 32 + 4);
    FragU a;
    a.q = make_uint4(pack_f16x2(lo.x, lo.y), pack_f16x2(lo.z, lo.w),
                     pack_f16x2(hi.x, hi.y), pack_f16x2(hi.z, hi.w));
#pragma unroll
    for (int ct = 0; ct < 4; ++ct) {
      const int n = cg * 64 + ct * 16 + mrow;
      FragU b;
      b.q = *reinterpret_cast<const uint4*>(&WT[n * 68 + kb * 16 + quad * 4]);
      acc[ct] = __builtin_amdgcn_mfma_f32_16x16x32_f16(a.f, b.f, acc[ct], 0, 0, 0);
    }
  }

#pragma unroll
  for (int ct = 0; ct < 4; ++ct) {
#pragma unroll
    for (int r = 0; r < 4; ++r) {
      const float v = acc[ct][r];
      const float vOdd = __shfl(v, lane | 1);
      if ((lane & 1) == 0) {
        const int row = n0 + quad * 4 + r;
        z1h[(size_t)row * 64 + cg * 32 + ct * 8 + (mrow >> 1)] = pack_f16x2(v, vOdd);
      }
    }
  }
}

// ---------------- agg1: half-wave per node, dwordx2 gather ----------------
// 2 nodes/wave. Lane covers dwords {2*(lane&31), +1} (= features 4il..4il+3)
// of its half's node. One load inst fetches TWO rows (one per half-wave).
// Batch of 16 insts = 32 rows in flight.
__global__ __launch_bounds__(256, 8) void agg1(
    const uint32_t* __restrict__ z1h, const int* __restrict__ adj,
    const int* __restrict__ cnt, const float* __restrict__ b1,
    const uint32_t* __restrict__ zpad, uint32_t* __restrict__ hh) {
  const int lane = threadIdx.x & 63;
  const int wid  = threadIdx.x >> 6;
  const int p  = blockIdx.x * 4 + wid;   // 6250 blocks -> p 0..24999
  const int nA = p * 2, nB = p * 2 + 1;
  const int il = lane & 31;
  const int myn = (lane < 32) ? nA : nB;

  // adjacency: lane holds slots {2il, 2il+1} of its node
  const int2 a2 = reinterpret_cast<const int2*>(adj)[(size_t)myn * 32 + il];
  const int c = cnt[myn];
  int dA = __builtin_amdgcn_readlane(c, 0);  if (dA > kCap) dA = kCap;
  int dB = __builtin_amdgcn_readlane(c, 32); if (dB > kCap) dB = kCap;
  const int dm = (dA > dB) ? dA : dB;

  // self
  const uint2 sv = *reinterpret_cast<const uint2*>(z1h + (size_t)myn * 64 + 2 * il);
  f16x2 ax0 = as_f16x2(sv.x), ay0 = as_f16x2(sv.y);
  f16x2 ax1 = (f16x2)0, ay1 = (f16x2)0, ax2 = (f16x2)0, ay2 = (f16x2)0,
        ax3 = (f16x2)0, ay3 = (f16x2)0;

  int e = 0;
  while (e < dm) {
    uint2 v[16];
#pragma unroll
    for (int j = 0; j < 16; ++j) {
      const int ee = e + j;
      const int sl = ee >> 1;
      const int rA = (ee & 1) ? __builtin_amdgcn_readlane(a2.y, sl)
                              : __builtin_amdgcn_readlane(a2.x, sl);
      const int rB = (ee & 1) ? __builtin_amdgcn_readlane(a2.y, 32 + sl)
                              : __builtin_amdgcn_readlane(a2.x, 32 + sl);
      const uint32_t* baseA = (ee < dA) ? (z1h + (size_t)rA * 64) : zpad;  // scalar
      const uint32_t* baseB = (ee < dB) ? (z1h + (size_t)rB * 64) : zpad;  // scalar
      const uint32_t* base = (lane < 32) ? baseA : baseB;  // per-lane select
      v[j] = *reinterpret_cast<const uint2*>(base + 2 * il);
    }
#pragma unroll
    for (int j = 0; j < 16; ++j) {
      const f16x2 vx = as_f16x2(v[j].x), vy = as_f16x2(v[j].y);
      if ((j & 3) == 0)      { ax0 += vx; ay0 += vy; }
      else if ((j & 3) == 1) { ax1 += vx; ay1 += vy; }
      else if ((j & 3) == 2) { ax2 += vx; ay2 += vy; }
      else                   { ax3 += vx; ay3 += vy; }
    }
    e += 16;
  }

  const f16x2 sx = (ax0 + ax1) + (ax2 + ax3);
  const f16x2 sy = (ay0 + ay1) + (ay2 + ay3);
  const float4 bb = *reinterpret_cast<const float4*>(b1 + 4 * il);
  float h0 = fmaxf(f16_lo(sx) + bb.x, 0.0f);
  float h1 = fmaxf(f16_hi(sx) + bb.y, 0.0f);
  float h2 = fmaxf(f16_lo(sy) + bb.z, 0.0f);
  float h3 = fmaxf(f16_hi(sy) + bb.w, 0.0f);
  const uint32_t j0 = (uint32_t)myn * 128u + 4u * (uint32_t)il;
  h0 = drop_elem(j0)      ? 0.0f : h0 * 2.0f;
  h1 = drop_elem(j0 + 1u) ? 0.0f : h1 * 2.0f;
  h2 = drop_elem(j0 + 2u) ? 0.0f : h2 * 2.0f;
  h3 = drop_elem(j0 + 3u) ? 0.0f : h3 * 2.0f;
  uint2 o = make_uint2(pack_f16x2(h0, h1), pack_f16x2(h2, h3));
  *reinterpret_cast<uint2*>(hh + (size_t)myn * 64 + 2 * il) = o;
}

// ---------------- GEMM2 (MFMA f16): z2h = pack_f16(h @ W2) ----------------
__global__ __launch_bounds__(256, 4) void gemm2_mfma(
    const uint32_t* __restrict__ hh, const uint32_t* __restrict__ W2T,
    uint32_t* __restrict__ z2h) {
  __shared__ uint32_t WT[64 * 68];  // 17 KB
  for (int v = threadIdx.x; v < 64 * 64; v += 256)
    WT[(v >> 6) * 68 + (v & 63)] = W2T[v];
  __syncthreads();

  const int lane = threadIdx.x & 63;
  const int wid  = threadIdx.x >> 6;
  const int rb   = blockIdx.x * 4 + wid;  // 782 blocks -> rb 0..3127
  if (rb >= 3125) return;
  const int n0   = rb * 16;
  const int quad = lane >> 4;
  const int mrow = lane & 15;

  const uint32_t* hp = hh + (size_t)(n0 + mrow) * 64 + quad * 4;
  f32x4 acc[4] = {{0.f,0.f,0.f,0.f},{0.f,0.f,0.f,0.f},{0.f,0.f,0.f,0.f},{0.f,0.f,0.f,0.f}};

#pragma unroll
  for (int kb = 0; kb < 4; ++kb) {
    FragU a;
    a.q = *reinterpret_cast<const uint4*>(hp + kb * 16);
#pragma unroll
    for (int ct = 0; ct < 4; ++ct) {
      const int n = ct * 16 + mrow;
      FragU b;
      b.q = *reinterpret_cast<const uint4*>(&WT[n * 68 + kb * 16 + quad * 4]);
      acc[ct] = __builtin_amdgcn_mfma_f32_16x16x32_f16(a.f, b.f, acc[ct], 0, 0, 0);
    }
  }

#pragma unroll
  for (int ct = 0; ct < 4; ++ct) {
#pragma unroll
    for (int r = 0; r < 4; ++r) {
      const float v = acc[ct][r];
      const float vOdd = __shfl(v, lane | 1);
      if ((lane & 1) == 0) {
        const int row = n0 + quad * 4 + r;
        z2h[(size_t)row * 32 + ct * 8 + (mrow >> 1)] = pack_f16x2(v, vOdd);
      }
    }
  }
}

// ---------------- agg_out: quarter-wave per node, dwordx2 gather ----------------
// 4 nodes/wave. 16-lane group g covers dwords {2*(lane&15), +1} of node 4p+g's
// 32-dword row. One load inst fetches FOUR rows; 16-inst batch = 64 rows in flight.
__global__ __launch_bounds__(256, 8) void agg_out(
    const uint32_t* __restrict__ z2h, const int* __restrict__ adj,
    const int* __restrict__ cnt, const float* __restrict__ b2,
    const uint32_t* __restrict__ zpad, float* __restrict__ out) {
  const int lane = threadIdx.x & 63;
  const int wid  = threadIdx.x >> 6;
  const int p = blockIdx.x * 4 + wid;   // 3125 blocks -> p 0..12499
  const int g  = lane >> 4;
  const int il = lane & 15;
  const int myn = p * 4 + g;

  // adjacency: lane holds slots {4il..4il+3} of its group's node
  const int4 a4 = reinterpret_cast<const int4*>(adj)[(size_t)myn * 16 + il];
  const int c = cnt[myn];
  int d0 = __builtin_amdgcn_readlane(c, 0);  if (d0 > kCap) d0 = kCap;
  int d1 = __builtin_amdgcn_readlane(c, 16); if (d1 > kCap) d1 = kCap;
  int d2 = __builtin_amdgcn_readlane(c, 32); if (d2 > kCap) d2 = kCap;
  int d3 = __builtin_amdgcn_readlane(c, 48); if (d3 > kCap) d3 = kCap;
  int dm = (d0 > d1) ? d0 : d1;
  if (d2 > dm) dm = d2;
  if (d3 > dm) dm = d3;

  const uint2 sv = *reinterpret_cast<const uint2*>(z2h + (size_t)myn * 32 + 2 * il);
  f16x2 ax0 = as_f16x2(sv.x), ay0 = as_f16x2(sv.y);
  f16x2 ax1 = (f16x2)0, ay1 = (f16x2)0, ax2 = (f16x2)0, ay2 = (f16x2)0,
        ax3 = (f16x2)0, ay3 = (f16x2)0;

  int e = 0;
  while (e < dm) {
    uint2 v[16];
#pragma unroll
    for (int j = 0; j < 16; ++j) {
      const int ee = e + j;
      const int sl = ee >> 2;
      int r0, r1, r2, r3;
      switch (j & 3) {  // compile-time component select (e is multiple of 4... of 16)
        case 0: r0 = __builtin_amdgcn_readlane(a4.x, sl);
                r1 = __builtin_amdgcn_readlane(a4.x, 16 + sl);
                r2 = __builtin_amdgcn_readlane(a4.x, 32 + sl);
                r3 = __builtin_amdgcn_readlane(a4.x, 48 + sl); break;
        case 1: r0 = __builtin_amdgcn_readlane(a4.y, sl);
                r1 = __builtin_amdgcn_readlane(a4.y, 16 + sl);
                r2 = __builtin_amdgcn_readlane(a4.y, 32 + sl);
                r3 = __builtin_amdgcn_readlane(a4.y, 48 + sl); break;
        case 2: r0 = __builtin_amdgcn_readlane(a4.z, sl);
                r1 = __builtin_amdgcn_readlane(a4.z, 16 + sl);
                r2 = __builtin_amdgcn_readlane(a4.z, 32 + sl);
                r3 = __builtin_amdgcn_readlane(a4.z, 48 + sl); break;
        default: r0 = __builtin_amdgcn_readlane(a4.w, sl);
                 r1 = __builtin_amdgcn_readlane(a4.w, 16 + sl);
                 r2 = __builtin_amdgcn_readlane(a4.w, 32 + sl);
                 r3 = __builtin_amdgcn_readlane(a4.w, 48 + sl); break;
      }
      const uint32_t* b0 = (ee < d0) ? (z2h + (size_t)r0 * 32) : zpad;  // scalar
      const uint32_t* b1p = (ee < d1) ? (z2h + (size_t)r1 * 32) : zpad;
      const uint32_t* b2p = (ee < d2) ? (z2h + (size_t)r2 * 32) : zpad;
      const uint32_t* b3 = (ee < d3) ? (z2h + (size_t)r3 * 32) : zpad;
      const uint32_t* lo = (g & 1) ? b1p : b0;   // per-lane selects
      const uint32_t* hi = (g & 1) ? b3 : b2p;
      const uint32_t* base = (g & 2) ? hi : lo;
      v[j] = *reinterpret_cast<const uint2*>(base + 2 * il);
    }
#pragma unroll
    for (int j = 0; j < 16; ++j) {
      const f16x2 vx = as_f16x2(v[j].x), vy = as_f16x2(v[j].y);
      if ((j & 3) == 0)      { ax0 += vx; ay0 += vy; }
      else if ((j & 3) == 1) { ax1 += vx; ay1 += vy; }
      else if ((j & 3) == 2) { ax2 += vx; ay2 += vy; }
      else                   { ax3 += vx; ay3 += vy; }
    }
    e += 16;
  }

  const f16x2 sx = (ax0 + ax1) + (ax2 + ax3);
  const f16x2 sy = (ay0 + ay1) + (ay2 + ay3);
  const float4 bb = *reinterpret_cast<const float4*>(b2 + 4 * il);
  const float4 o = make_float4(f16_lo(sx) + bb.x, f16_hi(sx) + bb.y,
                               f16_lo(sy) + bb.z, f16_hi(sy) + bb.w);
  *reinterpret_cast<float4*>(out + (size_t)myn * 64 + 4 * il) = o;
}

// ---------------- launch ----------------
extern "C" void kernel_launch(void* const* d_in, const int* in_sizes, int n_in,
                              void* d_out, int out_size, void* d_ws, size_t ws_size,
                              hipStream_t stream) {
  const float* x  = (const float*)d_in[0];
  const int*   ei = (const int*)d_in[1];
  const float* W1 = (const float*)d_in[2];
  const float* b1 = (const float*)d_in[3];
  const float* W2 = (const float*)d_in[4];
  const float* b2 = (const float*)d_in[5];
  float* out = (float*)d_out;

  const int E = in_sizes[1] / 2;  // edge_index is (2, E), int32 on device
  const int* src = ei;
  const int* dst = ei + E;

  // d_ws layout:
  uint32_t* zpad = (uint32_t*)d_ws;                        // 64 dwords = 256 B, zeroed
  int*      cnt  = (int*)((char*)d_ws + 256);              // 50000 ints
  int*      adj  = cnt + kN;                               // 50000*64 ints = 12.8 MB
  uint32_t* z1h  = (uint32_t*)(adj + (size_t)kN * kCap);   // 50000*64 dwords = 12.8 MB
  uint32_t* hh   = z1h + (size_t)kN * 64;                  // 50000*64 dwords = 12.8 MB
  uint32_t* z2h  = hh + (size_t)kN * 64;                   // 50000*32 dwords = 6.4 MB
  uint32_t* W1T  = z2h + (size_t)kN * 32;                  // 8192 dwords = 32 KB
  uint32_t* W2T  = W1T + 128 * 64;                         // 4096 dwords = 16 KB

  const int adjBlocks = (E + 1023) / 1024;  // 4 edges/thread

  hipMemsetAsync(d_ws, 0, 256 + (size_t)kN * sizeof(int), stream);  // zpad + cnt
  k0_prep_build<<<kPrepBlocks + adjBlocks, 256, 0, stream>>>(
      W1, W2, W1T, W2T, src, dst, cnt, adj, E);
  gemm1_mfma<<<1563, 256, 0, stream>>>(x, W1T, z1h);
  agg1<<<6250, 256, 0, stream>>>(z1h, adj, cnt, b1, zpad, hh);
  gemm2_mfma<<<782, 256, 0, stream>>>(hh, W2T, z2h);
  agg_out<<<3125, 256, 0, stream>>>(z2h, adj, cnt, b2, zpad, out);
}

// Round 14
// 185.191 us; speedup vs baseline: 7.0328x; 1.0354x over previous
//
#include <hip/hip_runtime.h>
#include <stdint.h>

static constexpr int kN   = 50000;   // nodes
static constexpr int kCap = 64;      // adjacency capacity per node (Poisson(12) tail @64 ~ 1e-25)
static constexpr int kPrepBlocks = 48;  // 48*256 = 12288 >= 128*64+64*64 weight dwords

typedef __attribute__((ext_vector_type(8))) _Float16 f16x8;  // MFMA A/B fragment
typedef __attribute__((ext_vector_type(2))) _Float16 f16x2;  // packed pair -> v_pk_add_f16
typedef __attribute__((ext_vector_type(4))) float f32x4;     // MFMA 16x16 accumulator

// ---------------- threefry2x32-20 (verified vs Random123 KAT) ----------------
__device__ __forceinline__ uint32_t rotl32(uint32_t v, uint32_t r) {
  return (v << r) | (v >> (32u - r));
}

__device__ __forceinline__ uint2 threefry2x32(uint32_t k0, uint32_t k1,
                                              uint32_t x0, uint32_t x1) {
  const uint32_t k2 = k0 ^ k1 ^ 0x1BD11BDAu;
  x0 += k0; x1 += k1;
#define TFR(r) { x0 += x1; x1 = rotl32(x1, r); x1 ^= x0; }
  TFR(13u) TFR(15u) TFR(26u) TFR(6u)
  x0 += k1; x1 += k2 + 1u;
  TFR(17u) TFR(29u) TFR(16u) TFR(24u)
  x0 += k2; x1 += k0 + 2u;
  TFR(13u) TFR(15u) TFR(26u) TFR(6u)
  x0 += k0; x1 += k1 + 3u;
  TFR(17u) TFR(29u) TFR(16u) TFR(24u)
  x0 += k1; x1 += k2 + 4u;
  TFR(13u) TFR(15u) TFR(26u) TFR(6u)
  x0 += k2; x1 += k0 + 5u;
#undef TFR
  return make_uint2(x0, x1);
}

__device__ __forceinline__ bool drop_elem(uint32_t j) {
  const uint2 r = threefry2x32(0u, 42u, 0u, j);
  return ((r.x ^ r.y) >> 31) != 0u;
}

// ---------------- f16 pack/unpack ----------------
union PairU { f16x2 h; uint32_t u; };
__device__ __forceinline__ uint32_t pack_f16x2(float lo, float hi) {
  PairU p; p.h[0] = (_Float16)lo; p.h[1] = (_Float16)hi; return p.u;
}
__device__ __forceinline__ float f16_lo(f16x2 v) { return (float)v[0]; }
__device__ __forceinline__ float f16_hi(f16x2 v) { return (float)v[1]; }

union FragU { uint4 q; f16x8 f; };

// ---------------- K0: prep_wT + build_adj (block-range split, both LDS-free) ----
__global__ __launch_bounds__(256) void k0_prep_build(
    const float* __restrict__ W1, const float* __restrict__ W2,
    uint32_t* __restrict__ W1T, uint32_t* __restrict__ W2T,
    const int* __restrict__ src, const int* __restrict__ dst,
    int* __restrict__ cnt, int* __restrict__ adj, int E) {
  if (blockIdx.x < kPrepBlocks) {
    const int v = blockIdx.x * 256 + threadIdx.x;
    if (v < 128 * 64) {
      const int n = v >> 6, i = v & 63;
      W1T[v] = pack_f16x2(W1[(size_t)(2 * i) * 128 + n], W1[(size_t)(2 * i + 1) * 128 + n]);
    } else if (v < 128 * 64 + 64 * 64) {
      const int w = v - 128 * 64;
      const int n = w >> 6, i = w & 63;
      W2T[w] = pack_f16x2(W2[(size_t)(2 * i) * 64 + n], W2[(size_t)(2 * i + 1) * 64 + n]);
    }
    return;
  }
  const int base = (blockIdx.x - kPrepBlocks) * 1024 + threadIdx.x;
  int d[4], s[4];
  bool ok[4];
#pragma unroll
  for (int j = 0; j < 4; ++j) {
    const int e = base + j * 256;
    ok[j] = (e < E);
    d[j] = ok[j] ? dst[e] : 0;
    s[j] = ok[j] ? src[e] : 0;
  }
  int slot[4];
#pragma unroll
  for (int j = 0; j < 4; ++j)
    slot[j] = ok[j] ? atomicAdd(&cnt[d[j]], 1) : kCap;
#pragma unroll
  for (int j = 0; j < 4; ++j)
    if (ok[j] && slot[j] < kCap) adj[d[j] * kCap + slot[j]] = s[j];
}

// ---------------- GEMM1 (MFMA f16): z1h = pack_f16(x @ W1) ----------------
// Wave = 16 rows x 64 cols: 4 kb x 4 ct MFMAs. A: x converted to f16 in-flight.
// B: W1T staged linearly into LDS (conflict-free), row stride 68 dwords.
// Layouts (HW-verified r8): A[m=lane&15][k=quad*8+j], B[n=lane&15][k=quad*8+j],
// D: col=lane&15, row=quad*4+reg.
__global__ __launch_bounds__(256, 4) void gemm1_mfma(
    const float* __restrict__ x, const uint32_t* __restrict__ W1T,
    uint32_t* __restrict__ z1h) {
  __shared__ uint32_t WT[128 * 68];  // 34 KB
  for (int v = threadIdx.x; v < 128 * 64; v += 256)
    WT[(v >> 6) * 68 + (v & 63)] = W1T[v];
  __syncthreads();

  const int lane = threadIdx.x & 63;
  const int wid  = threadIdx.x >> 6;
  const int rb   = blockIdx.x * 2 + (wid >> 1);  // 1563 blocks -> rb 0..3125
  if (rb >= 3125) return;
  const int cg   = wid & 1;
  const int n0   = rb * 16;
  const int quad = lane >> 4;
  const int mrow = lane & 15;

  const float* xp = x + (size_t)(n0 + mrow) * 128 + quad * 8;
  f32x4 acc[4] = {{0.f,0.f,0.f,0.f},{0.f,0.f,0.f,0.f},{0.f,0.f,0.f,0.f},{0.f,0.f,0.f,0.f}};

#pragma unroll
  for (int kb = 0; kb < 4; ++kb) {
    const float4 lo = *reinterpret_cast<const float4*>(xp + kb * 32);
    const float4 hi = *reinterpret_cast<const float4*>(xp + kb * 32 + 4);
    FragU a;
    a.q = make_uint4(pack_f16x2(lo.x, lo.y), pack_f16x2(lo.z, lo.w),
                     pack_f16x2(hi.x, hi.y), pack_f16x2(hi.z, hi.w));
#pragma unroll
    for (int ct = 0; ct < 4; ++ct) {
      const int n = cg * 64 + ct * 16 + mrow;
      FragU b;
      b.q = *reinterpret_cast<const uint4*>(&WT[n * 68 + kb * 16 + quad * 4]);
      acc[ct] = __builtin_amdgcn_mfma_f32_16x16x32_f16(a.f, b.f, acc[ct], 0, 0, 0);
    }
  }

#pragma unroll
  for (int ct = 0; ct < 4; ++ct) {
#pragma unroll
    for (int r = 0; r < 4; ++r) {
      const float v = acc[ct][r];
      const float vOdd = __shfl(v, lane | 1);
      if ((lane & 1) == 0) {
        const int row = n0 + quad * 4 + r;
        z1h[(size_t)row * 64 + cg * 32 + ct * 8 + (mrow >> 1)] = pack_f16x2(v, vOdd);
      }
    }
  }
}

// ---------------- agg1: hh = pack_f16(dropout(relu(z1[n] + sum z1[adj] + b1))) ----------------
// 2 nodes per wave, 32 loads in flight (explicit value arrays). No LDS.
__global__ __launch_bounds__(256, 8) void agg1(
    const f16x2* __restrict__ z1h, const int* __restrict__ adj,
    const int* __restrict__ cnt, const float* __restrict__ b1,
    const f16x2* __restrict__ zpad, uint32_t* __restrict__ hh) {
  const int lane = threadIdx.x & 63;
  const int wid  = threadIdx.x >> 6;
  const int p  = blockIdx.x * 4 + wid;   // 6250 blocks
  const int nA = p * 2, nB = p * 2 + 1;

  const int vaA = adj[(size_t)nA * kCap + lane];
  const int vaB = adj[(size_t)nB * kCap + lane];
  int dA = __builtin_amdgcn_readfirstlane(cnt[nA]); if (dA > kCap) dA = kCap;
  int dB = __builtin_amdgcn_readfirstlane(cnt[nB]); if (dB > kCap) dB = kCap;
  const int dm = (dA > dB) ? dA : dB;

  f16x2 sA0 = z1h[(size_t)nA * 64 + lane];  // self
  f16x2 sB0 = z1h[(size_t)nB * 64 + lane];
  f16x2 sA1 = (f16x2)0, sA2 = (f16x2)0, sA3 = (f16x2)0;
  f16x2 sB1 = (f16x2)0, sB2 = (f16x2)0, sB3 = (f16x2)0;

  int e = 0;
  while (e < dm) {
    f16x2 vA[16], vB[16];
#pragma unroll
    for (int j = 0; j < 16; ++j) {
      const int ee = e + j;
      const int ia = __builtin_amdgcn_readlane(vaA, ee);
      const f16x2* ba = (ee < dA) ? (z1h + (size_t)ia * 64) : zpad;  // scalar select
      vA[j] = ba[lane];
    }
#pragma unroll
    for (int j = 0; j < 16; ++j) {
      const int ee = e + j;
      const int ib = __builtin_amdgcn_readlane(vaB, ee);
      const f16x2* bb = (ee < dB) ? (z1h + (size_t)ib * 64) : zpad;
      vB[j] = bb[lane];
    }
#pragma unroll
    for (int j = 0; j < 16; ++j) {
      if ((j & 3) == 0)      { sA0 += vA[j]; sB0 += vB[j]; }
      else if ((j & 3) == 1) { sA1 += vA[j]; sB1 += vB[j]; }
      else if ((j & 3) == 2) { sA2 += vA[j]; sB2 += vB[j]; }
      else                   { sA3 += vA[j]; sB3 += vB[j]; }
    }
    e += 16;
  }

  const float2 bb = *reinterpret_cast<const float2*>(b1 + 2 * lane);
  {
    const f16x2 s = (sA0 + sA1) + (sA2 + sA3);
    float hx = fmaxf(f16_lo(s) + bb.x, 0.0f);
    float hy = fmaxf(f16_hi(s) + bb.y, 0.0f);
    const uint32_t j0 = (uint32_t)nA * 128u + 2u * (uint32_t)lane;
    hx = drop_elem(j0)      ? 0.0f : hx * 2.0f;
    hy = drop_elem(j0 + 1u) ? 0.0f : hy * 2.0f;
    hh[(size_t)nA * 64 + lane] = pack_f16x2(hx, hy);
  }
  {
    const f16x2 s = (sB0 + sB1) + (sB2 + sB3);
    float hx = fmaxf(f16_lo(s) + bb.x, 0.0f);
    float hy = fmaxf(f16_hi(s) + bb.y, 0.0f);
    const uint32_t j0 = (uint32_t)nB * 128u + 2u * (uint32_t)lane;
    hx = drop_elem(j0)      ? 0.0f : hx * 2.0f;
    hy = drop_elem(j0 + 1u) ? 0.0f : hy * 2.0f;
    hh[(size_t)nB * 64 + lane] = pack_f16x2(hx, hy);
  }
}

// ---------------- GEMM2 (MFMA f16): z2h = pack_f16(h @ W2) ----------------
// W2T staged linearly into LDS (conflict-free). A-fragment = 4 dwords of hh.
__global__ __launch_bounds__(256, 4) void gemm2_mfma(
    const uint32_t* __restrict__ hh, const uint32_t* __restrict__ W2T,
    uint32_t* __restrict__ z2h) {
  __shared__ uint32_t WT[64 * 68];  // 17 KB
  for (int v = threadIdx.x; v < 64 * 64; v += 256)
    WT[(v >> 6) * 68 + (v & 63)] = W2T[v];
  __syncthreads();

  const int lane = threadIdx.x & 63;
  const int wid  = threadIdx.x >> 6;
  const int rb   = blockIdx.x * 4 + wid;  // 782 blocks -> rb 0..3127
  if (rb >= 3125) return;
  const int n0   = rb * 16;
  const int quad = lane >> 4;
  const int mrow = lane & 15;

  const uint32_t* hp = hh + (size_t)(n0 + mrow) * 64 + quad * 4;
  f32x4 acc[4] = {{0.f,0.f,0.f,0.f},{0.f,0.f,0.f,0.f},{0.f,0.f,0.f,0.f},{0.f,0.f,0.f,0.f}};

#pragma unroll
  for (int kb = 0; kb < 4; ++kb) {
    FragU a;
    a.q = *reinterpret_cast<const uint4*>(hp + kb * 16);
#pragma unroll
    for (int ct = 0; ct < 4; ++ct) {
      const int n = ct * 16 + mrow;
      FragU b;
      b.q = *reinterpret_cast<const uint4*>(&WT[n * 68 + kb * 16 + quad * 4]);
      acc[ct] = __builtin_amdgcn_mfma_f32_16x16x32_f16(a.f, b.f, acc[ct], 0, 0, 0);
    }
  }

#pragma unroll
  for (int ct = 0; ct < 4; ++ct) {
#pragma unroll
    for (int r = 0; r < 4; ++r) {
      const float v = acc[ct][r];
      const float vOdd = __shfl(v, lane | 1);
      if ((lane & 1) == 0) {
        const int row = n0 + quad * 4 + r;
        z2h[(size_t)row * 32 + ct * 8 + (mrow >> 1)] = pack_f16x2(v, vOdd);
      }
    }
  }
}

// ---------------- agg2: out = z2[n] + sum z2[adj] + b2 (width 64, f16 rows) ----------------
// 2 nodes per wave. Row = 32 dwords; all 64 lanes accumulate word (lane&31)
// (lanes 32-63 mirror, same lines); one end shuffle unpacks the feature lane.
__global__ __launch_bounds__(256, 8) void agg_out(
    const f16x2* __restrict__ z2h, const int* __restrict__ adj,
    const int* __restrict__ cnt, const float* __restrict__ b2,
    const f16x2* __restrict__ zpad, float* __restrict__ out) {
  const int lane = threadIdx.x & 63;
  const int wid  = threadIdx.x >> 6;
  const int p  = blockIdx.x * 4 + wid;   // 6250 blocks
  const int nA = p * 2, nB = p * 2 + 1;
  const int word = lane & 31;

  const int vaA = adj[(size_t)nA * kCap + lane];
  const int vaB = adj[(size_t)nB * kCap + lane];
  int dA = __builtin_amdgcn_readfirstlane(cnt[nA]); if (dA > kCap) dA = kCap;
  int dB = __builtin_amdgcn_readfirstlane(cnt[nB]); if (dB > kCap) dB = kCap;
  const int dm = (dA > dB) ? dA : dB;

  f16x2 sA0 = z2h[(size_t)nA * 32 + word];  // self
  f16x2 sB0 = z2h[(size_t)nB * 32 + word];
  f16x2 sA1 = (f16x2)0, sA2 = (f16x2)0, sA3 = (f16x2)0;
  f16x2 sB1 = (f16x2)0, sB2 = (f16x2)0, sB3 = (f16x2)0;

  int e = 0;
  while (e < dm) {
    f16x2 vA[16], vB[16];
#pragma unroll
    for (int j = 0; j < 16; ++j) {
      const int ee = e + j;
      const int ia = __builtin_amdgcn_readlane(vaA, ee);
      const f16x2* ba = (ee < dA) ? (z2h + (size_t)ia * 32) : zpad;
      vA[j] = ba[word];
    }
#pragma unroll
    for (int j = 0; j < 16; ++j) {
      const int ee = e + j;
      const int ib = __builtin_amdgcn_readlane(vaB, ee);
      const f16x2* bb = (ee < dB) ? (z2h + (size_t)ib * 32) : zpad;
      vB[j] = bb[word];
    }
#pragma unroll
    for (int j = 0; j < 16; ++j) {
      if ((j & 3) == 0)      { sA0 += vA[j]; sB0 += vB[j]; }
      else if ((j & 3) == 1) { sA1 += vA[j]; sB1 += vB[j]; }
      else if ((j & 3) == 2) { sA2 += vA[j]; sB2 += vB[j]; }
      else                   { sA3 += vA[j]; sB3 += vB[j]; }
    }
    e += 16;
  }

  const float bias = b2[lane];
  {
    PairU s; s.h = (sA0 + sA1) + (sA2 + sA3);
    PairU g; g.u = (uint32_t)__shfl((int)s.u, lane >> 1);
    const float v = (lane & 1) ? f16_hi(g.h) : f16_lo(g.h);
    out[(size_t)nA * 64 + lane] = v + bias;
  }
  {
    PairU s; s.h = (sB0 + sB1) + (sB2 + sB3);
    PairU g; g.u = (uint32_t)__shfl((int)s.u, lane >> 1);
    const float v = (lane & 1) ? f16_hi(g.h) : f16_lo(g.h);
    out[(size_t)nB * 64 + lane] = v + bias;
  }
}

// ---------------- launch ----------------
extern "C" void kernel_launch(void* const* d_in, const int* in_sizes, int n_in,
                              void* d_out, int out_size, void* d_ws, size_t ws_size,
                              hipStream_t stream) {
  const float* x  = (const float*)d_in[0];
  const int*   ei = (const int*)d_in[1];
  const float* W1 = (const float*)d_in[2];
  const float* b1 = (const float*)d_in[3];
  const float* W2 = (const float*)d_in[4];
  const float* b2 = (const float*)d_in[5];
  float* out = (float*)d_out;

  const int E = in_sizes[1] / 2;  // edge_index is (2, E), int32 on device
  const int* src = ei;
  const int* dst = ei + E;

  // d_ws layout:
  uint32_t* zpad = (uint32_t*)d_ws;                        // 64 dwords = 256 B, zeroed
  int*      cnt  = (int*)((char*)d_ws + 256);              // 50000 ints
  int*      adj  = cnt + kN;                               // 50000*64 ints = 12.8 MB
  uint32_t* z1h  = (uint32_t*)(adj + (size_t)kN * kCap);   // 50000*64 dwords = 12.8 MB
  uint32_t* hh   = z1h + (size_t)kN * 64;                  // 50000*64 dwords = 12.8 MB
  uint32_t* z2h  = hh + (size_t)kN * 64;                   // 50000*32 dwords = 6.4 MB
  uint32_t* W1T  = z2h + (size_t)kN * 32;                  // 8192 dwords = 32 KB
  uint32_t* W2T  = W1T + 128 * 64;                         // 4096 dwords = 16 KB

  const int adjBlocks = (E + 1023) / 1024;  // 4 edges/thread

  hipMemsetAsync(d_ws, 0, 256 + (size_t)kN * sizeof(int), stream);  // zpad + cnt
  k0_prep_build<<<kPrepBlocks + adjBlocks, 256, 0, stream>>>(
      W1, W2, W1T, W2T, src, dst, cnt, adj, E);
  gemm1_mfma<<<1563, 256, 0, stream>>>(x, W1T, z1h);
  agg1<<<6250, 256, 0, stream>>>((const f16x2*)z1h, adj, cnt, b1, (const f16x2*)zpad, hh);
  gemm2_mfma<<<782, 256, 0, stream>>>(hh, W2T, z2h);
  agg_out<<<6250, 256, 0, stream>>>((const f16x2*)z2h, adj, cnt, b2, (const f16x2*)zpad, out);
}